// Round 1
// baseline (94.233 us; speedup 1.0000x reference)
//
#include <hip/hip_runtime.h>
#include <math.h>

#define K_DCG 512
// SIGMA == 1.0f folded in. N = 8192 fixed by harness (code assumes N == 8192).

typedef float v2f __attribute__((ext_vector_type(2)));

// ---------------------------------------------------------------------------
// R19: fused SINGLE-dispatch EXACT pairwise evaluation (no table, no interp,
// no atomics, no workspace, no cross-block dependency).
// Math (same verified decomposition as R13/R15/R16):
//   lam_i = Ninv*[ P_i + a_i*S1_i + Sa_i - g_i*Sd_i - d_i*Sg_i ]
//   P_i   = g_i*sufD_b - a_i*sufC_b - sufGD_b + d_i*sufG_b   (buckets > b_i)
//   S*_i  = sum_j w_j / (1 + e^{p_i} * e^{-p_j}),  w = {1, d_j, g_j, g_j*d_j}
// computed EXACTLY (derivation re-verified: rho-part  = sum rho*(gi-gj)(di-dj)
// = a_i*S1 + Sa - g_i*Sd - d_i*Sg since same-bucket pairs vanish (gi==gj);
// Sij-part = P_i since rank ascending => b_j>b_i implies d_j>... handled by
// suffix scalars; diagonal j==i contributes 0).
// Structure: 256 blocks x 256 thr. Block owns 32 i's (one 32-chunk => ballot
// tie-break works in epilogue). Thread = (ilocal = tid&31, slice = tid>>5).
// Per block: ge-scan -> scalars -> 8 chunks of { compute 1024 j-records into
// LDS (ballot-rank, same verified machinery), sweep 128 j's per thread } ->
// slice-reduce -> epilogue.
// Total pair work 67M evals ~ 15 issue-cyc/wave-iter => ~6.5us VALU; removes
// the 2nd dispatch, the Fg atomic table, interp error (absmax 3.9e-3 -> ~1e-4)
// and K2's 32-block tail.
// ---------------------------------------------------------------------------

__global__ __launch_bounds__(256) void lambdarank_kernel(
        const float* __restrict__ pred, const float* __restrict__ targ,
        float* __restrict__ out, int N) {
    const int tid = threadIdx.x, bid = blockIdx.x;
    const int wave = tid >> 6, lane = tid & 63;

    __shared__ int s_cnt[4][256];              // ge-level chunk counts -> excl prefix
    __shared__ int s_tot4[4];
    __shared__ int s_base[6];
    __shared__ float s_red[4][5];
    __shared__ float s_scal[21];  // [0]=ninv [1..5]=sufD [6..10]=sufG [11..15]=sufGD [16..20]=sufC
    __shared__ float4 s_jt[1024];              // current 1024-j chunk: {d,g,em,a}
    __shared__ float s_part[4][32][4];         // per-wave slice-pair partials

    // my i and e^{+p_i} (8 threads per i -> broadcast load)
    const int ilocal = tid & 31;
    const int slice  = tid >> 5;
    const int myi    = bid * 32 + ilocal;
    const float exi  = __expf(pred[myi]);

    // 1. per-thread chunk [tid*32, tid*32+32): ge-level counts
    {
        int c1 = 0, c2 = 0, c3 = 0, c4 = 0;
        const float4* t4 = (const float4*)targ;
        #pragma unroll
        for (int k = 0; k < 8; k++) {
            const float4 v = t4[tid * 8 + k];
            #pragma unroll
            for (int e = 0; e < 4; e++) {
                const float tv = ((const float*)&v)[e];
                c1 += (tv >= 1.0f); c2 += (tv >= 2.0f);
                c3 += (tv >= 3.0f); c4 += (tv >= 4.0f);
            }
        }
        s_cnt[0][tid] = c1; s_cnt[1][tid] = c2;
        s_cnt[2][tid] = c3; s_cnt[3][tid] = c4;
    }
    __syncthreads();

    // 2. exclusive scan over the 256 chunk-counts (wave w -> ge-level w+1)
    {
        int carry = 0;
        for (int c = 0; c < 4; c++) {
            const int orig = s_cnt[wave][c * 64 + lane];
            int v = orig;
            #pragma unroll
            for (int off = 1; off < 64; off <<= 1) {
                const int nv = __shfl_up(v, off, 64);
                if (lane >= off) v += nv;
            }
            s_cnt[wave][c * 64 + lane] = v - orig + carry;
            carry += __shfl(v, 63, 64);
        }
        if (lane == 0) s_tot4[wave] = carry;
    }
    __syncthreads();

    // 3. bucket bases: base[b] = #elements with t < b
    if (tid < 6)
        s_base[tid] = (tid == 0) ? 0 : (tid == 5 ? N : N - s_tot4[tid - 1]);
    __syncthreads();

    // 4. D_ge sums + maxDCG + suffix scalars (verbatim verified R8/R9 machinery)
    {
        const int base1 = N - s_tot4[0], base2 = N - s_tot4[1];
        const int base3 = N - s_tot4[2], base4 = N - s_tot4[3];
        float Dge1 = 0, Dge2 = 0, Dge3 = 0, Dge4 = 0, md = 0;
        for (int r = tid; r < N; r += 256) {
            const float term = __builtin_amdgcn_rcpf(log2f((float)(r + 2)));
            Dge1 += (r >= base1) ? term : 0.0f;
            Dge2 += (r >= base2) ? term : 0.0f;
            Dge3 += (r >= base3) ? term : 0.0f;
            Dge4 += (r >= base4) ? term : 0.0f;
        }
        for (int pos = tid + 1; pos <= K_DCG; pos += 256) {
            const int r0 = N - pos;
            const int b = (r0 >= base1) + (r0 >= base2) + (r0 >= base3) + (r0 >= base4);
            md += ((float)(1 << b) - 1.0f) * __builtin_amdgcn_rcpf(log2f((float)(pos + 1)));
        }
        #pragma unroll
        for (int off = 32; off; off >>= 1) {
            Dge1 += __shfl_down(Dge1, off, 64);
            Dge2 += __shfl_down(Dge2, off, 64);
            Dge3 += __shfl_down(Dge3, off, 64);
            Dge4 += __shfl_down(Dge4, off, 64);
            md   += __shfl_down(md,   off, 64);
        }
        if (lane == 0) {
            s_red[wave][0] = Dge1; s_red[wave][1] = Dge2;
            s_red[wave][2] = Dge3; s_red[wave][3] = Dge4; s_red[wave][4] = md;
        }
    }
    __syncthreads();
    if (tid == 0) {
        float Dge[6];
        Dge[0] = 0.0f; Dge[5] = 0.0f;
        #pragma unroll
        for (int k = 1; k <= 4; k++)
            Dge[k] = s_red[0][k-1] + s_red[1][k-1] + s_red[2][k-1] + s_red[3][k-1];
        const float mdt = s_red[0][4] + s_red[1][4] + s_red[2][4] + s_red[3][4];
        s_scal[0] = __builtin_amdgcn_rcpf(mdt);            // Ninv
        float sufG = 0.0f, sufGD = 0.0f;
        for (int b = 4; b >= 0; b--) {
            s_scal[1 + b]  = Dge[b + 1];                   // sufD_b
            s_scal[6 + b]  = sufG;
            s_scal[11 + b] = sufGD;
            s_scal[16 + b] = (float)(N - s_base[b + 1]);   // sufC_b
            const float Db = Dge[b] - Dge[b + 1];
            const float gb = (float)(1 << b);
            sufG  += gb * (float)(s_base[b + 1] - s_base[b]);
            sufGD += gb * Db;
        }
    }

    // 5. chunk loop: build 1024 j-records in LDS, then sweep them.
    v2f dg = 0.0f, oa = 0.0f;                  // {Sd, Sg}, {S1, Sa}
    for (int c = 0; c < 8; c++) {
        __syncthreads();                        // previous sweep done / scalars done
        #pragma unroll
        for (int r = 0; r < 4; r++) {
            const int idx = c * 1024 + r * 256 + tid;
            const float tv = targ[idx], pv = pred[idx];
            const int b = (tv >= 1.0f) + (tv >= 2.0f) + (tv >= 3.0f) + (tv >= 4.0f);
            unsigned long long mym = 0;
            #pragma unroll
            for (int bb = 0; bb < 5; bb++) {
                const unsigned long long m = __ballot(b == bb);
                if (b == bb) mym = m;
            }
            const unsigned long long half_mask =
                (lane < 32) ? 0x00000000FFFFFFFFull : 0xFFFFFFFF00000000ull;
            const int tie = __popcll(mym & half_mask & ((1ull << lane) - 1ull));
            const int ch = idx >> 5;           // global 32-chunk (half-wave aligned)
            const int pA = (b == 0) ? ch * 32 : s_cnt[b - 1][ch];
            const int pB = (b == 4) ? 0 : s_cnt[b][ch];
            const int rank = s_base[b] + (pA - pB) + tie;
            const float d = __builtin_amdgcn_rcpf(log2f((float)(rank + 2)));
            const float g = (float)(1 << b);
            s_jt[r * 256 + tid] = make_float4(d, g, __expf(-pv), g * d);
        }
        __syncthreads();
        // sweep: this thread's 128-j slice of the chunk, broadcast LDS reads
        const float4* jt = &s_jt[slice * 128];
        #pragma unroll 4
        for (int jj = 0; jj < 128; jj++) {
            const float4 e = jt[jj];
            const float r = __builtin_amdgcn_rcpf(fmaf(exi, e.z, 1.0f));
            v2f wdg; wdg.x = e.x; wdg.y = e.y;
            v2f woa; woa.x = 1.0f; woa.y = e.w;
            dg += r * wdg;                     // v_pk_fma_f32
            oa += r * woa;
        }
    }

    // 6. reduce the 8 slices per i: halves within wave, then across 4 waves.
    dg.x += __shfl_xor(dg.x, 32, 64);
    dg.y += __shfl_xor(dg.y, 32, 64);
    oa.x += __shfl_xor(oa.x, 32, 64);
    oa.y += __shfl_xor(oa.y, 32, 64);
    if (lane < 32) {
        s_part[wave][lane][0] = dg.x; s_part[wave][lane][1] = dg.y;
        s_part[wave][lane][2] = oa.x; s_part[wave][lane][3] = oa.y;
    }
    __syncthreads();

    // 7. epilogue: 32 threads, one i each (block's i's = one 32-chunk => ballot
    //    tie-break over lanes 0..31 is exact).
    if (tid < 32) {
        const float Sd = s_part[0][tid][0] + s_part[1][tid][0] + s_part[2][tid][0] + s_part[3][tid][0];
        const float Sg = s_part[0][tid][1] + s_part[1][tid][1] + s_part[2][tid][1] + s_part[3][tid][1];
        const float S1 = s_part[0][tid][2] + s_part[1][tid][2] + s_part[2][tid][2] + s_part[3][tid][2];
        const float Sa = s_part[0][tid][3] + s_part[1][tid][3] + s_part[2][tid][3] + s_part[3][tid][3];

        const int i = bid * 32 + tid;
        const float tv = targ[i];
        const int b = (tv >= 1.0f) + (tv >= 2.0f) + (tv >= 3.0f) + (tv >= 4.0f);
        unsigned long long mym = 0;
        #pragma unroll
        for (int bb = 0; bb < 5; bb++) {
            const unsigned long long m = __ballot(b == bb);
            if (b == bb) mym = m;
        }
        const int tie = __popcll(mym & ((1ull << tid) - 1ull));
        const int ch = i >> 5;                 // == bid
        const int pA = (b == 0) ? ch * 32 : s_cnt[b - 1][ch];
        const int pB = (b == 4) ? 0 : s_cnt[b][ch];
        const int rank = s_base[b] + (pA - pB) + tie;
        const float d = __builtin_amdgcn_rcpf(log2f((float)(rank + 2)));
        const float g = (float)(1 << b);
        const float a = g * d;
        const float P = g * s_scal[1 + b] - a * s_scal[16 + b]
                        - s_scal[11 + b] + d * s_scal[6 + b];
        out[i] = s_scal[0] * (P + a * S1 + Sa - g * Sd - d * Sg);
    }
}

// ---------------------------------------------------------------------------
extern "C" void kernel_launch(void* const* d_in, const int* in_sizes, int n_in,
                              void* d_out, int out_size, void* d_ws, size_t ws_size,
                              hipStream_t stream) {
    const float* pred = (const float*)d_in[0];
    const float* targ = (const float*)d_in[1];
    float* out = (float*)d_out;
    const int N = in_sizes[0];   // 8192
    (void)d_ws; (void)ws_size;   // workspace unused: no table, no atomics

    lambdarank_kernel<<<256, 256, 0, stream>>>(pred, targ, out, N);
}

// Round 2
// 78.109 us; speedup vs baseline: 1.2064x; 1.2064x over previous
//
#include <hip/hip_runtime.h>
#include <math.h>

#define K_DCG 512
// SIGMA == 1.0f folded in. N = 8192 fixed by harness (code assumes N == 8192).

typedef float v2f __attribute__((ext_vector_type(2)));

// ---------------------------------------------------------------------------
// R20 = R19 structure with 1024-thread blocks (occupancy fix).
// R19 post-mortem: 256thr x 256blk = 1 wave/SIMD -> ds_read_b128 (~120cy) +
// v_rcp latency un-hidden -> VALUBusy 31%, kernel 45.5us. This version: same
// verified math, 1024 threads/block (4 waves/SIMD), each thread sweeps 256
// j's (32 slices per i). Scan/scalar phases run as tid<256 sub-phase
// (verbatim verified R8/R9 machinery, wave-uniform branch, no inner barrier).
// Math (verified R13..R19):
//   lam_i = Ninv*[ P_i + a_i*S1_i + Sa_i - g_i*Sd_i - d_i*Sg_i ]
//   P_i   = g_i*sufD_b - a_i*sufC_b - sufGD_b + d_i*sufG_b   (buckets > b_i)
//   S*_i  = sum_j w_j / (1 + e^{p_i} * e^{-p_j}),  w = {1, d_j, g_j, g_j*d_j}
// Single dispatch, no workspace, no atomics, no cross-block dependency.
// ---------------------------------------------------------------------------

__global__ __launch_bounds__(1024) void lambdarank_kernel(
        const float* __restrict__ pred, const float* __restrict__ targ,
        float* __restrict__ out, int N) {
    const int tid = threadIdx.x, bid = blockIdx.x;
    const int wave = tid >> 6, lane = tid & 63;

    __shared__ int s_cnt[4][256];              // ge-level 32-chunk counts -> excl prefix
    __shared__ int s_tot4[4];
    __shared__ int s_base[6];
    __shared__ float s_red[4][5];
    __shared__ float s_scal[21];  // [0]=ninv [1..5]=sufD [6..10]=sufG [11..15]=sufGD [16..20]=sufC
    __shared__ float4 s_jt[1024];              // current 1024-j chunk: {d,g,em,a}
    __shared__ float s_part[16][32][4];        // per-wave slice-pair partials

    // my i and e^{+p_i} (32 threads per i -> broadcast load)
    const int ilocal = tid & 31;
    const int slice  = tid >> 5;               // 0..31
    const int myi    = bid * 32 + ilocal;
    const float exi  = __expf(pred[myi]);

    // 1. ge-level counts over 32-element chunks (256 scan threads, verified)
    if (tid < 256) {
        int c1 = 0, c2 = 0, c3 = 0, c4 = 0;
        const float4* t4 = (const float4*)targ;
        #pragma unroll
        for (int k = 0; k < 8; k++) {
            const float4 v = t4[tid * 8 + k];
            #pragma unroll
            for (int e = 0; e < 4; e++) {
                const float tv = ((const float*)&v)[e];
                c1 += (tv >= 1.0f); c2 += (tv >= 2.0f);
                c3 += (tv >= 3.0f); c4 += (tv >= 4.0f);
            }
        }
        s_cnt[0][tid] = c1; s_cnt[1][tid] = c2;
        s_cnt[2][tid] = c3; s_cnt[3][tid] = c4;
    }
    __syncthreads();

    // 2. exclusive scan over the 256 chunk-counts (wave w -> ge-level w+1)
    if (tid < 256) {
        int carry = 0;
        for (int c = 0; c < 4; c++) {
            const int orig = s_cnt[wave][c * 64 + lane];
            int v = orig;
            #pragma unroll
            for (int off = 1; off < 64; off <<= 1) {
                const int nv = __shfl_up(v, off, 64);
                if (lane >= off) v += nv;
            }
            s_cnt[wave][c * 64 + lane] = v - orig + carry;
            carry += __shfl(v, 63, 64);
        }
        if (lane == 0) s_tot4[wave] = carry;
    }
    __syncthreads();

    // 3. bucket bases: base[b] = #elements with t < b
    if (tid < 6)
        s_base[tid] = (tid == 0) ? 0 : (tid == 5 ? N : N - s_tot4[tid - 1]);
    __syncthreads();

    // 4. D_ge sums + maxDCG + suffix scalars (verbatim verified R8/R9 machinery)
    if (tid < 256) {
        const int base1 = N - s_tot4[0], base2 = N - s_tot4[1];
        const int base3 = N - s_tot4[2], base4 = N - s_tot4[3];
        float Dge1 = 0, Dge2 = 0, Dge3 = 0, Dge4 = 0, md = 0;
        for (int r = tid; r < N; r += 256) {
            const float term = __builtin_amdgcn_rcpf(log2f((float)(r + 2)));
            Dge1 += (r >= base1) ? term : 0.0f;
            Dge2 += (r >= base2) ? term : 0.0f;
            Dge3 += (r >= base3) ? term : 0.0f;
            Dge4 += (r >= base4) ? term : 0.0f;
        }
        for (int pos = tid + 1; pos <= K_DCG; pos += 256) {
            const int r0 = N - pos;
            const int b = (r0 >= base1) + (r0 >= base2) + (r0 >= base3) + (r0 >= base4);
            md += ((float)(1 << b) - 1.0f) * __builtin_amdgcn_rcpf(log2f((float)(pos + 1)));
        }
        #pragma unroll
        for (int off = 32; off; off >>= 1) {
            Dge1 += __shfl_down(Dge1, off, 64);
            Dge2 += __shfl_down(Dge2, off, 64);
            Dge3 += __shfl_down(Dge3, off, 64);
            Dge4 += __shfl_down(Dge4, off, 64);
            md   += __shfl_down(md,   off, 64);
        }
        if (lane == 0) {
            s_red[wave][0] = Dge1; s_red[wave][1] = Dge2;
            s_red[wave][2] = Dge3; s_red[wave][3] = Dge4; s_red[wave][4] = md;
        }
    }
    __syncthreads();
    if (tid == 0) {
        float Dge[6];
        Dge[0] = 0.0f; Dge[5] = 0.0f;
        #pragma unroll
        for (int k = 1; k <= 4; k++)
            Dge[k] = s_red[0][k-1] + s_red[1][k-1] + s_red[2][k-1] + s_red[3][k-1];
        const float mdt = s_red[0][4] + s_red[1][4] + s_red[2][4] + s_red[3][4];
        s_scal[0] = __builtin_amdgcn_rcpf(mdt);            // Ninv
        float sufG = 0.0f, sufGD = 0.0f;
        for (int b = 4; b >= 0; b--) {
            s_scal[1 + b]  = Dge[b + 1];                   // sufD_b
            s_scal[6 + b]  = sufG;
            s_scal[11 + b] = sufGD;
            s_scal[16 + b] = (float)(N - s_base[b + 1]);   // sufC_b
            const float Db = Dge[b] - Dge[b + 1];
            const float gb = (float)(1 << b);
            sufG  += gb * (float)(s_base[b + 1] - s_base[b]);
            sufGD += gb * Db;
        }
    }

    // 5. chunk loop: 1024 threads build 1024 j-records, then sweep 32 each.
    v2f dg = 0.0f, oa = 0.0f;                  // {Sd, Sg}, {S1, Sa}
    for (int c = 0; c < 8; c++) {
        __syncthreads();                        // prev sweep done / scalars visible
        {
            const int idx = c * 1024 + tid;
            const float tv = targ[idx], pv = pred[idx];
            const int b = (tv >= 1.0f) + (tv >= 2.0f) + (tv >= 3.0f) + (tv >= 4.0f);
            unsigned long long mym = 0;
            #pragma unroll
            for (int bb = 0; bb < 5; bb++) {
                const unsigned long long m = __ballot(b == bb);
                if (b == bb) mym = m;
            }
            const unsigned long long half_mask =
                (lane < 32) ? 0x00000000FFFFFFFFull : 0xFFFFFFFF00000000ull;
            const int tie = __popcll(mym & half_mask & ((1ull << lane) - 1ull));
            const int ch = idx >> 5;           // global 32-chunk (half-wave aligned)
            const int pA = (b == 0) ? ch * 32 : s_cnt[b - 1][ch];
            const int pB = (b == 4) ? 0 : s_cnt[b][ch];
            const int rank = s_base[b] + (pA - pB) + tie;
            const float d = __builtin_amdgcn_rcpf(log2f((float)(rank + 2)));
            const float g = (float)(1 << b);
            s_jt[tid] = make_float4(d, g, __expf(-pv), g * d);
        }
        __syncthreads();
        // sweep: this thread's 32-j slice of the chunk, broadcast LDS reads
        const float4* jt = &s_jt[slice * 32];
        #pragma unroll 8
        for (int jj = 0; jj < 32; jj++) {
            const float4 e = jt[jj];
            const float r = __builtin_amdgcn_rcpf(fmaf(exi, e.z, 1.0f));
            v2f wdg; wdg.x = e.x; wdg.y = e.y;
            v2f woa; woa.x = 1.0f; woa.y = e.w;
            dg += r * wdg;                     // v_pk_fma_f32
            oa += r * woa;
        }
    }

    // 6. reduce 32 slices per i: adjacent slice-pair within wave, then 16 waves.
    dg.x += __shfl_xor(dg.x, 32, 64);
    dg.y += __shfl_xor(dg.y, 32, 64);
    oa.x += __shfl_xor(oa.x, 32, 64);
    oa.y += __shfl_xor(oa.y, 32, 64);
    if (lane < 32) {
        s_part[wave][lane][0] = dg.x; s_part[wave][lane][1] = dg.y;
        s_part[wave][lane][2] = oa.x; s_part[wave][lane][3] = oa.y;
    }
    __syncthreads();

    // 7. epilogue: 32 threads (wave 0, lanes 0..31), one i each; block's i's
    //    = one 32-chunk so the ballot tie-break over lanes 0..31 is exact
    //    (lanes 32..63 inactive -> ballot bits 0).
    if (tid < 32) {
        float Sd = 0, Sg = 0, S1 = 0, Sa = 0;
        #pragma unroll
        for (int w = 0; w < 16; w++) {
            Sd += s_part[w][tid][0]; Sg += s_part[w][tid][1];
            S1 += s_part[w][tid][2]; Sa += s_part[w][tid][3];
        }
        const int i = bid * 32 + tid;
        const float tv = targ[i];
        const int b = (tv >= 1.0f) + (tv >= 2.0f) + (tv >= 3.0f) + (tv >= 4.0f);
        unsigned long long mym = 0;
        #pragma unroll
        for (int bb = 0; bb < 5; bb++) {
            const unsigned long long m = __ballot(b == bb);
            if (b == bb) mym = m;
        }
        const int tie = __popcll(mym & ((1ull << tid) - 1ull));
        const int ch = i >> 5;                 // == bid
        const int pA = (b == 0) ? ch * 32 : s_cnt[b - 1][ch];
        const int pB = (b == 4) ? 0 : s_cnt[b][ch];
        const int rank = s_base[b] + (pA - pB) + tie;
        const float d = __builtin_amdgcn_rcpf(log2f((float)(rank + 2)));
        const float g = (float)(1 << b);
        const float a = g * d;
        const float P = g * s_scal[1 + b] - a * s_scal[16 + b]
                        - s_scal[11 + b] + d * s_scal[6 + b];
        out[i] = s_scal[0] * (P + a * S1 + Sa - g * Sd - d * Sg);
    }
}

// ---------------------------------------------------------------------------
extern "C" void kernel_launch(void* const* d_in, const int* in_sizes, int n_in,
                              void* d_out, int out_size, void* d_ws, size_t ws_size,
                              hipStream_t stream) {
    const float* pred = (const float*)d_in[0];
    const float* targ = (const float*)d_in[1];
    float* out = (float*)d_out;
    const int N = in_sizes[0];   // 8192
    (void)d_ws; (void)ws_size;   // workspace unused: no table, no atomics

    lambdarank_kernel<<<256, 1024, 0, stream>>>(pred, targ, out, N);
}